// Round 1
// baseline (152.150 us; speedup 1.0000x reference)
//
#include <hip/hip_runtime.h>

#define BB 2
#define NN 768
#define FF 128
#define HH 128
#define TS 32
#define ROWS 4
#define THR 4e-3f

// f64 edge-MLP margin: m += sum_c wd_c * relu(p0*a_c + p1*b_c + beta_c)
// Exactly the math of the previous (passing) kernel; used only for |m32| < THR.
__device__ __attribute__((noinline))
double mlp_f64(const double* __restrict__ wpack, double p0, double p1, double m) {
#pragma unroll 1
    for (int c = 0; c < HH; ++c) {
        double2 wab = *(const double2*)&wpack[4 * c];        // a, b
        double2 wbw = *(const double2*)&wpack[4 * c + 2];    // beta, wd
        double t = fma(p1, wab.y, fma(p0, wab.x, wbw.x));
        t = fmax(t, 0.0);
        m = fma(t, wbw.y, m);
    }
    return m;
}

__device__ inline float decide(float m32, double p0, double p1, double init,
                               const double* __restrict__ wpack) {
    // |m32 - m64| < ~2e-4 worst-case (see analysis); 4e-3 threshold = 20x margin.
    if (__builtin_expect(fabsf(m32) < THR, 0))
        return mlp_f64(wpack, p0, p1, init) > 0.0 ? 1.0f : 0.0f;
    return m32 > 0.0f ? 1.0f : 0.0f;
}

// k1: feats = relu(X@w1+b1)@w2+b2 (f64 accum); Xc[b,k,i,d] = X[b,i,2d+k] + gate*feats[2d+k]
// block 0 additionally packs the score-MLP weights (f64 + f32) — absorbs old k0.
__global__ __launch_bounds__(128)
void edgefeat_kernel(const float* __restrict__ X,
                     const float* __restrict__ w1, const float* __restrict__ b1,
                     const float* __restrict__ w2, const float* __restrict__ b2,
                     const float* __restrict__ gatep,
                     const float* __restrict__ sm_w1, const float* __restrict__ sm_b1,
                     const float* __restrict__ sm_w2,
                     double* __restrict__ Xc,
                     double* __restrict__ wpack,
                     float4* __restrict__ wpackf) {
    __shared__ float  Xs[ROWS][FF];
    __shared__ double Hs[ROWS][HH];
    const int h = threadIdx.x;            // 0..127 output column
    const int row0 = blockIdx.x * ROWS;   // global row in [0, B*N)
    for (int r = 0; r < ROWS; ++r) Xs[r][h] = X[(size_t)(row0 + r) * FF + h];
    if (blockIdx.x == 0) {
        // pack score-MLP weights: wpack[c] = {w1[0,c], w1[1,c], b1[c], w2[c,1]-w2[c,0]}
        double a  = (double)sm_w1[h];
        double bq = (double)sm_w1[HH + h];
        double be = (double)sm_b1[h];
        double wd = (double)sm_w2[2 * h + 1] - (double)sm_w2[2 * h + 0];
        wpack[4 * h + 0] = a;
        wpack[4 * h + 1] = bq;
        wpack[4 * h + 2] = be;
        wpack[4 * h + 3] = wd;
        wpackf[h] = make_float4((float)a, (float)bq, (float)be, (float)wd);
    }
    __syncthreads();
    double acc[ROWS];
    double bb = (double)b1[h];
    for (int r = 0; r < ROWS; ++r) acc[r] = bb;
    for (int f = 0; f < FF; ++f) {
        double w = (double)w1[f * HH + h];        // coalesced across h
        for (int r = 0; r < ROWS; ++r) acc[r] = fma((double)Xs[r][f], w, acc[r]);
    }
    for (int r = 0; r < ROWS; ++r) Hs[r][h] = acc[r] > 0.0 ? acc[r] : 0.0;
    __syncthreads();
    bb = (double)b2[h];
    for (int r = 0; r < ROWS; ++r) acc[r] = bb;
    for (int c = 0; c < HH; ++c) {
        double w = (double)w2[c * HH + h];
        for (int r = 0; r < ROWS; ++r) acc[r] = fma(Hs[r][c], w, acc[r]);
    }
    const double gate = (double)gatep[0];
    const int k = h & 1, d = h >> 1;
    const int b = row0 / NN;
    const int i0 = row0 % NN;
    for (int r = 0; r < ROWS; ++r) {
        double v = (double)Xs[r][h] + gate * acc[r];
        Xc[(((size_t)(b * 2 + k)) * NN + (i0 + r)) * 64 + d] = v;
    }
}

// k2: per 32x32 tile (ti<=tj): gram (D=64, f64) -> edge MLP (f32 fast / f64 fallback)
//     -> gumbel argmax -> symmetric write
__global__ __launch_bounds__(256, 2)
void edge_decide_kernel(const double* __restrict__ Xc,
                        const double* __restrict__ wpack,
                        const float4* __restrict__ wpackf,
                        const float* __restrict__ sm_b2,
                        const float* __restrict__ gumbel,
                        float* __restrict__ out) {
    const int ti = blockIdx.x, tj = blockIdx.y, b = blockIdx.z;
    if (tj < ti) return;
    __shared__ double Ai[2][TS][66];   // pad 66: breaks pow2 bank stride, keeps 16B align
    __shared__ double Aj[2][TS][66];
    __shared__ float  As[TS][TS + 1];
    const int tid = threadIdx.x;
    const int i0 = ti * TS, j0 = tj * TS;

    // stage Xc tiles (coalesced double2 global reads)
    for (int q = 0; q < 8; ++q) {
        int flat = tid + 256 * q;           // pair index 0..2047
        int k  = flat >> 10;
        int r  = (flat >> 5) & 31;
        int dp = flat & 31;
        size_t base = ((size_t)(b * 2 + k)) * NN;
        double2 vi = *(const double2*)&Xc[(base + i0 + r) * 64 + 2 * dp];
        *(double2*)&Ai[k][r][2 * dp] = vi;
        double2 vj = *(const double2*)&Xc[(base + j0 + r) * 64 + 2 * dp];
        *(double2*)&Aj[k][r][2 * dp] = vj;
    }
    __syncthreads();

    const int rh = tid >> 4;         // 0..15
    const int ch = tid & 15;         // 0..15
    const int r0 = rh, r1 = rh + 16;
    const int c0 = 2 * ch, c1 = c0 + 1;

    // gram: p[k][re][ce]  (f64 — exact inputs for the fallback path)
    double p000 = 0, p001 = 0, p010 = 0, p011 = 0;
    double p100 = 0, p101 = 0, p110 = 0, p111 = 0;
    for (int d2 = 0; d2 < 32; ++d2) {
        double2 a00 = *(const double2*)&Ai[0][r0][2 * d2];
        double2 a01 = *(const double2*)&Ai[0][r1][2 * d2];
        double2 a10 = *(const double2*)&Ai[1][r0][2 * d2];
        double2 a11 = *(const double2*)&Ai[1][r1][2 * d2];
        double2 b00 = *(const double2*)&Aj[0][c0][2 * d2];
        double2 b01 = *(const double2*)&Aj[0][c1][2 * d2];
        double2 b10 = *(const double2*)&Aj[1][c0][2 * d2];
        double2 b11 = *(const double2*)&Aj[1][c1][2 * d2];
        p000 = fma(a00.y, b00.y, fma(a00.x, b00.x, p000));
        p001 = fma(a00.y, b01.y, fma(a00.x, b01.x, p001));
        p010 = fma(a01.y, b00.y, fma(a01.x, b00.x, p010));
        p011 = fma(a01.y, b01.y, fma(a01.x, b01.x, p011));
        p100 = fma(a10.y, b10.y, fma(a10.x, b10.x, p100));
        p101 = fma(a10.y, b11.y, fma(a10.x, b11.x, p101));
        p110 = fma(a11.y, b10.y, fma(a11.x, b10.x, p110));
        p111 = fma(a11.y, b11.y, fma(a11.x, b11.x, p111));
    }

    // margin init: (b2[1]-b2[0]) + (g1-g0) per edge; gumbel only matters at upper (i,j)
    const double bd = (double)sm_b2[1] - (double)sm_b2[0];
    float4 g0v = *(const float4*)&gumbel[(((size_t)b * NN + i0 + r0) * NN + j0 + c0) * 2];
    float4 g1v = *(const float4*)&gumbel[(((size_t)b * NN + i0 + r1) * NN + j0 + c0) * 2];
    double i00 = bd + ((double)g0v.y - (double)g0v.x);
    double i01 = bd + ((double)g0v.w - (double)g0v.z);
    double i10 = bd + ((double)g1v.y - (double)g1v.x);
    double i11 = bd + ((double)g1v.w - (double)g1v.z);

    // f32 fast-path edge MLP (weights via uniform float4 loads)
    float m00 = (float)i00, m01 = (float)i01, m10 = (float)i10, m11 = (float)i11;
    float q000 = (float)p000, q001 = (float)p001, q010 = (float)p010, q011 = (float)p011;
    float q100 = (float)p100, q101 = (float)p101, q110 = (float)p110, q111 = (float)p111;
    for (int c = 0; c < HH; ++c) {
        float4 wf = wpackf[c];     // {a, b, beta, wd}
        float t;
        t = fmaf(q100, wf.y, fmaf(q000, wf.x, wf.z)); t = fmaxf(t, 0.0f); m00 = fmaf(t, wf.w, m00);
        t = fmaf(q101, wf.y, fmaf(q001, wf.x, wf.z)); t = fmaxf(t, 0.0f); m01 = fmaf(t, wf.w, m01);
        t = fmaf(q110, wf.y, fmaf(q010, wf.x, wf.z)); t = fmaxf(t, 0.0f); m10 = fmaf(t, wf.w, m10);
        t = fmaf(q111, wf.y, fmaf(q011, wf.x, wf.z)); t = fmaxf(t, 0.0f); m11 = fmaf(t, wf.w, m11);
    }

    float A00 = decide(m00, p000, p100, i00, wpack);
    float A01 = decide(m01, p001, p101, i01, wpack);
    float A10 = decide(m10, p010, p110, i10, wpack);
    float A11 = decide(m11, p011, p111, i11, wpack);

    As[r0][c0] = A00; As[r0][c1] = A01;
    As[r1][c0] = A10; As[r1][c1] = A11;
    __syncthreads();

    if (ti != tj) {
        // direct tile (i<j guaranteed)
        *(float2*)&out[((size_t)b * NN + i0 + r0) * NN + j0 + c0] = make_float2(A00, A01);
        *(float2*)&out[((size_t)b * NN + i0 + r1) * NN + j0 + c0] = make_float2(A10, A11);
        // transposed tile: out[b, j0+jr, i0+ic] = As[ic][jr]
        float2 t0 = make_float2(As[c0][r0], As[c1][r0]);
        *(float2*)&out[((size_t)b * NN + j0 + r0) * NN + i0 + c0] = t0;
        float2 t1 = make_float2(As[c0][r1], As[c1][r1]);
        *(float2*)&out[((size_t)b * NN + j0 + r1) * NN + i0 + c0] = t1;
    } else {
        // diagonal tile: upper value mirrored, diag = 0
        float v00 = (r0 < c0) ? As[r0][c0] : ((r0 > c0) ? As[c0][r0] : 0.0f);
        float v01 = (r0 < c1) ? As[r0][c1] : ((r0 > c1) ? As[c1][r0] : 0.0f);
        float v10 = (r1 < c0) ? As[r1][c0] : ((r1 > c0) ? As[c0][r1] : 0.0f);
        float v11 = (r1 < c1) ? As[r1][c1] : ((r1 > c1) ? As[c1][r1] : 0.0f);
        *(float2*)&out[((size_t)b * NN + i0 + r0) * NN + j0 + c0] = make_float2(v00, v01);
        *(float2*)&out[((size_t)b * NN + i0 + r1) * NN + j0 + c0] = make_float2(v10, v11);
    }
}

extern "C" void kernel_launch(void* const* d_in, const int* in_sizes, int n_in,
                              void* d_out, int out_size, void* d_ws, size_t ws_size,
                              hipStream_t stream) {
    const float* X      = (const float*)d_in[0];
    const float* ef_w1  = (const float*)d_in[1];
    const float* ef_b1  = (const float*)d_in[2];
    const float* ef_w2  = (const float*)d_in[3];
    const float* ef_b2  = (const float*)d_in[4];
    const float* gate   = (const float*)d_in[5];
    const float* sm_w1  = (const float*)d_in[6];
    const float* sm_b1  = (const float*)d_in[7];
    const float* sm_w2  = (const float*)d_in[8];
    const float* sm_b2  = (const float*)d_in[9];
    const float* gumbel = (const float*)d_in[10];
    float* out = (float*)d_out;

    double* Xc     = (double*)d_ws;                       // B*2*N*64 doubles = 1.5 MiB
    double* wpack  = Xc + (size_t)BB * 2 * NN * 64;       // 512 doubles
    float4* wpackf = (float4*)(wpack + 4 * HH);           // 128 float4

    edgefeat_kernel<<<BB * NN / ROWS, 128, 0, stream>>>(
        X, ef_w1, ef_b1, ef_w2, ef_b2, gate, sm_w1, sm_b1, sm_w2, Xc, wpack, wpackf);
    dim3 grid(NN / TS, NN / TS, BB);
    edge_decide_kernel<<<grid, 256, 0, stream>>>(Xc, wpack, wpackf, sm_b2, gumbel, out);
}

// Round 2
// 150.031 us; speedup vs baseline: 1.0141x; 1.0141x over previous
//
#include <hip/hip_runtime.h>

#define BB 2
#define NN 768
#define FF 128
#define HH 128
#define TS 32
#define NT (NN / TS)                 // 24 tiles per dim
#define NPAIR (NT * (NT + 1) / 2)    // 300 upper-triangular tile pairs
#define EROWS 2
#define THR 4e-3f

// ---- exact f64 slow path: recompute gram from global Xc + f64 MLP --------
// Bit-identical to the original always-f64 kernel (same values, same fma order).
__device__ __attribute__((noinline))
double edge_exact_f64(const double* __restrict__ Xc, const double* __restrict__ wpack,
                      int b, int i, int j, double init) {
    const double* xi0 = Xc + ((size_t)(b * 2 + 0) * NN + i) * 64;
    const double* xj0 = Xc + ((size_t)(b * 2 + 0) * NN + j) * 64;
    const double* xi1 = Xc + ((size_t)(b * 2 + 1) * NN + i) * 64;
    const double* xj1 = Xc + ((size_t)(b * 2 + 1) * NN + j) * 64;
    double p0 = 0.0, p1 = 0.0;
#pragma unroll 1
    for (int d2 = 0; d2 < 32; ++d2) {
        double2 a0 = *(const double2*)&xi0[2 * d2];
        double2 b0 = *(const double2*)&xj0[2 * d2];
        double2 a1 = *(const double2*)&xi1[2 * d2];
        double2 b1 = *(const double2*)&xj1[2 * d2];
        p0 = fma(a0.y, b0.y, fma(a0.x, b0.x, p0));
        p1 = fma(a1.y, b1.y, fma(a1.x, b1.x, p1));
    }
    double m = init;
#pragma unroll 1
    for (int c = 0; c < HH; ++c) {
        double2 wab = *(const double2*)&wpack[4 * c];        // a, b
        double2 wbw = *(const double2*)&wpack[4 * c + 2];    // beta, wd
        double tt = fma(p1, wab.y, fma(p0, wab.x, wbw.x));
        tt = fmax(tt, 0.0);
        m = fma(tt, wbw.y, m);
    }
    return m;
}

__device__ inline float decide(float m32, const double* __restrict__ Xc,
                               const double* __restrict__ wpack,
                               int b, int i, int j, double init) {
    // |m32 - m64| practical ~4e-4 (f32 gram + f32 MLP); THR = 4e-3 = 10x margin.
    if (__builtin_expect(fabsf(m32) < THR, 0))
        return edge_exact_f64(Xc, wpack, b, i, j, init) > 0.0 ? 1.0f : 0.0f;
    return m32 > 0.0f ? 1.0f : 0.0f;
}

// k1: feats = relu(X@w1+b1)@w2+b2 (f64 accum); Xc (f64) and Xcf (f32) both written.
// block 0 additionally packs the score-MLP weights (f64 + f32).
__global__ __launch_bounds__(128)
void edgefeat_kernel(const float* __restrict__ X,
                     const float* __restrict__ w1, const float* __restrict__ b1,
                     const float* __restrict__ w2, const float* __restrict__ b2,
                     const float* __restrict__ gatep,
                     const float* __restrict__ sm_w1, const float* __restrict__ sm_b1,
                     const float* __restrict__ sm_w2,
                     double* __restrict__ Xc, float* __restrict__ Xcf,
                     double* __restrict__ wpack, float4* __restrict__ wpackf) {
    __shared__ float  Xs[EROWS][FF];
    __shared__ double Hs[EROWS][HH];
    const int h = threadIdx.x;            // 0..127 output column
    const int row0 = blockIdx.x * EROWS;  // global row in [0, B*N)
    for (int r = 0; r < EROWS; ++r) Xs[r][h] = X[(size_t)(row0 + r) * FF + h];
    if (blockIdx.x == 0) {
        // wpack[c] = {w1[0,c], w1[1,c], b1[c], w2[c,1]-w2[c,0]}
        double a  = (double)sm_w1[h];
        double bq = (double)sm_w1[HH + h];
        double be = (double)sm_b1[h];
        double wd = (double)sm_w2[2 * h + 1] - (double)sm_w2[2 * h + 0];
        wpack[4 * h + 0] = a;  wpack[4 * h + 1] = bq;
        wpack[4 * h + 2] = be; wpack[4 * h + 3] = wd;
        wpackf[h] = make_float4((float)a, (float)bq, (float)be, (float)wd);
    }
    __syncthreads();
    double acc[EROWS];
    double bb = (double)b1[h];
    for (int r = 0; r < EROWS; ++r) acc[r] = bb;
    for (int f = 0; f < FF; ++f) {
        double w = (double)w1[f * HH + h];        // coalesced across h
        for (int r = 0; r < EROWS; ++r) acc[r] = fma((double)Xs[r][f], w, acc[r]);
    }
    for (int r = 0; r < EROWS; ++r) Hs[r][h] = acc[r] > 0.0 ? acc[r] : 0.0;
    __syncthreads();
    bb = (double)b2[h];
    for (int r = 0; r < EROWS; ++r) acc[r] = bb;
    for (int c = 0; c < HH; ++c) {
        double w = (double)w2[c * HH + h];
        for (int r = 0; r < EROWS; ++r) acc[r] = fma(Hs[r][c], w, acc[r]);
    }
    const double gate = (double)gatep[0];
    const int k = h & 1, d = h >> 1;
    const int b = row0 / NN;
    const int i0 = row0 % NN;
    for (int r = 0; r < EROWS; ++r) {
        double v = (double)Xs[r][h] + gate * acc[r];
        size_t idx = (((size_t)(b * 2 + k)) * NN + (i0 + r)) * 64 + d;
        Xc[idx]  = v;
        Xcf[idx] = (float)v;
    }
}

// k2: per upper-tri 32x32 tile: f32 gram -> f32 edge MLP (weights in LDS)
//     -> sign decision with rare exact-f64 re-compute -> symmetric write.
__global__ __launch_bounds__(256, 4)
void edge_decide_kernel(const double* __restrict__ Xc,
                        const float* __restrict__ Xcf,
                        const double* __restrict__ wpack,
                        const float4* __restrict__ wpackf,
                        const float* __restrict__ sm_b2,
                        const float* __restrict__ gumbel,
                        float* __restrict__ out) {
    __shared__ float  Ai[2][TS][66];   // stride 66 floats: 2-way bank alias only (free)
    __shared__ float  Aj[2][TS][66];
    __shared__ float4 Wl[HH];          // score-MLP packed weights (broadcast reads)
    __shared__ float  As[TS][TS + 1];
    const int b = blockIdx.y;
    const int t = blockIdx.x;
    // decode upper-triangular pair index: t -> (ti, tj), tj >= ti   (T=24)
    int ti = (int)((49.0 - sqrt(2401.0 - 8.0 * (double)t)) * 0.5);
    int base = ti * (49 - ti) / 2;
    if (t < base) { --ti; base = ti * (49 - ti) / 2; }
    else { int nb = (ti + 1) * (48 - ti) / 2; if (t >= nb) { ++ti; base = nb; } }
    const int tj = t - base + ti;
    const int tid = threadIdx.x;
    const int i0 = ti * TS, j0 = tj * TS;

    if (tid < HH) Wl[tid] = wpackf[tid];
    // stage f32 Xcf tiles (coalesced float2 global reads)
    for (int q = 0; q < 8; ++q) {
        int flat = tid + 256 * q;        // pair index over (k, r, d2)
        int d2 = flat & 31;
        int r  = (flat >> 5) & 31;
        int k  = flat >> 10;
        size_t rowbase = ((size_t)(b * 2 + k)) * NN;
        float2 vi = *(const float2*)&Xcf[(rowbase + i0 + r) * 64 + 2 * d2];
        *(float2*)&Ai[k][r][2 * d2] = vi;
        float2 vj = *(const float2*)&Xcf[(rowbase + j0 + r) * 64 + 2 * d2];
        *(float2*)&Aj[k][r][2 * d2] = vj;
    }
    __syncthreads();

    const int rh = tid >> 4;         // 0..15
    const int ch = tid & 15;         // 0..15
    const int r0 = rh, r1 = rh + 16;
    const int c0 = 2 * ch, c1 = c0 + 1;

    // f32 gram: p[k][re][ce]
    float p000 = 0.f, p001 = 0.f, p010 = 0.f, p011 = 0.f;
    float p100 = 0.f, p101 = 0.f, p110 = 0.f, p111 = 0.f;
    for (int d2 = 0; d2 < 32; ++d2) {
        float2 a00 = *(const float2*)&Ai[0][r0][2 * d2];
        float2 a01 = *(const float2*)&Ai[0][r1][2 * d2];
        float2 a10 = *(const float2*)&Ai[1][r0][2 * d2];
        float2 a11 = *(const float2*)&Ai[1][r1][2 * d2];
        float2 b00 = *(const float2*)&Aj[0][c0][2 * d2];
        float2 b01 = *(const float2*)&Aj[0][c1][2 * d2];
        float2 b10 = *(const float2*)&Aj[1][c0][2 * d2];
        float2 b11 = *(const float2*)&Aj[1][c1][2 * d2];
        p000 = fmaf(a00.y, b00.y, fmaf(a00.x, b00.x, p000));
        p001 = fmaf(a00.y, b01.y, fmaf(a00.x, b01.x, p001));
        p010 = fmaf(a01.y, b00.y, fmaf(a01.x, b00.x, p010));
        p011 = fmaf(a01.y, b01.y, fmaf(a01.x, b01.x, p011));
        p100 = fmaf(a10.y, b10.y, fmaf(a10.x, b10.x, p100));
        p101 = fmaf(a10.y, b11.y, fmaf(a10.x, b11.x, p101));
        p110 = fmaf(a11.y, b10.y, fmaf(a11.x, b10.x, p110));
        p111 = fmaf(a11.y, b11.y, fmaf(a11.x, b11.x, p111));
    }

    // margin init: (b2[1]-b2[0]) + (g1-g0) per edge (f64 kept for exact fallback init)
    const double bd = (double)sm_b2[1] - (double)sm_b2[0];
    float4 g0v = *(const float4*)&gumbel[(((size_t)b * NN + i0 + r0) * NN + j0 + c0) * 2];
    float4 g1v = *(const float4*)&gumbel[(((size_t)b * NN + i0 + r1) * NN + j0 + c0) * 2];
    double i00 = bd + ((double)g0v.y - (double)g0v.x);
    double i01 = bd + ((double)g0v.w - (double)g0v.z);
    double i10 = bd + ((double)g1v.y - (double)g1v.x);
    double i11 = bd + ((double)g1v.w - (double)g1v.z);

    // f32 edge MLP, weights from LDS (uniform address -> broadcast)
    float m00 = (float)i00, m01 = (float)i01, m10 = (float)i10, m11 = (float)i11;
    for (int c = 0; c < HH; ++c) {
        float4 wf = Wl[c];     // {a, b, beta, wd}
        float tt;
        tt = fmaf(p100, wf.y, fmaf(p000, wf.x, wf.z)); tt = fmaxf(tt, 0.f); m00 = fmaf(tt, wf.w, m00);
        tt = fmaf(p101, wf.y, fmaf(p001, wf.x, wf.z)); tt = fmaxf(tt, 0.f); m01 = fmaf(tt, wf.w, m01);
        tt = fmaf(p110, wf.y, fmaf(p010, wf.x, wf.z)); tt = fmaxf(tt, 0.f); m10 = fmaf(tt, wf.w, m10);
        tt = fmaf(p111, wf.y, fmaf(p011, wf.x, wf.z)); tt = fmaxf(tt, 0.f); m11 = fmaf(tt, wf.w, m11);
    }

    const int gi0 = i0 + r0, gi1 = i0 + r1;
    const int gj0 = j0 + c0, gj1 = j0 + c1;
    float A00 = decide(m00, Xc, wpack, b, gi0, gj0, i00);
    float A01 = decide(m01, Xc, wpack, b, gi0, gj1, i01);
    float A10 = decide(m10, Xc, wpack, b, gi1, gj0, i10);
    float A11 = decide(m11, Xc, wpack, b, gi1, gj1, i11);

    As[r0][c0] = A00; As[r0][c1] = A01;
    As[r1][c0] = A10; As[r1][c1] = A11;
    __syncthreads();

    if (ti != tj) {
        // direct tile (i<j guaranteed)
        *(float2*)&out[((size_t)b * NN + gi0) * NN + gj0] = make_float2(A00, A01);
        *(float2*)&out[((size_t)b * NN + gi1) * NN + gj0] = make_float2(A10, A11);
        // transposed tile: out[b, j0+jr, i0+ic] = As[ic][jr]
        float2 t0 = make_float2(As[c0][r0], As[c1][r0]);
        *(float2*)&out[((size_t)b * NN + j0 + r0) * NN + i0 + c0] = t0;
        float2 t1 = make_float2(As[c0][r1], As[c1][r1]);
        *(float2*)&out[((size_t)b * NN + j0 + r1) * NN + i0 + c0] = t1;
    } else {
        // diagonal tile: upper value mirrored, diag = 0
        float v00 = (r0 < c0) ? As[r0][c0] : ((r0 > c0) ? As[c0][r0] : 0.0f);
        float v01 = (r0 < c1) ? As[r0][c1] : ((r0 > c1) ? As[c1][r0] : 0.0f);
        float v10 = (r1 < c0) ? As[r1][c0] : ((r1 > c0) ? As[c0][r1] : 0.0f);
        float v11 = (r1 < c1) ? As[r1][c1] : ((r1 > c1) ? As[c1][r1] : 0.0f);
        *(float2*)&out[((size_t)b * NN + gi0) * NN + gj0] = make_float2(v00, v01);
        *(float2*)&out[((size_t)b * NN + gi1) * NN + gj0] = make_float2(v10, v11);
    }
}

extern "C" void kernel_launch(void* const* d_in, const int* in_sizes, int n_in,
                              void* d_out, int out_size, void* d_ws, size_t ws_size,
                              hipStream_t stream) {
    const float* X      = (const float*)d_in[0];
    const float* ef_w1  = (const float*)d_in[1];
    const float* ef_b1  = (const float*)d_in[2];
    const float* ef_w2  = (const float*)d_in[3];
    const float* ef_b2  = (const float*)d_in[4];
    const float* gate   = (const float*)d_in[5];
    const float* sm_w1  = (const float*)d_in[6];
    const float* sm_b1  = (const float*)d_in[7];
    const float* sm_w2  = (const float*)d_in[8];
    const float* sm_b2  = (const float*)d_in[9];
    const float* gumbel = (const float*)d_in[10];
    float* out = (float*)d_out;

    double* Xc     = (double*)d_ws;                         // 2*2*768*64 doubles = 1.5 MiB
    double* wpack  = Xc + (size_t)BB * 2 * NN * 64;         // 512 doubles
    float4* wpackf = (float4*)(wpack + 4 * HH);             // 128 float4
    float*  Xcf    = (float*)(wpackf + HH);                 // 768 KiB f32 copy

    edgefeat_kernel<<<BB * NN / EROWS, 128, 0, stream>>>(
        X, ef_w1, ef_b1, ef_w2, ef_b2, gate, sm_w1, sm_b1, sm_w2, Xc, Xcf, wpack, wpackf);
    dim3 grid(NPAIR, BB);
    edge_decide_kernel<<<grid, 256, 0, stream>>>(Xc, Xcf, wpack, wpackf, sm_b2, gumbel, out);
}

// Round 3
// 131.850 us; speedup vs baseline: 1.1540x; 1.1379x over previous
//
#include <hip/hip_runtime.h>

#define BB 2
#define NN 768
#define FF 128
#define HH 128
#define TS 32
#define NT (NN / TS)                 // 24 tiles per dim
#define NPAIR (NT * (NT + 1) / 2)    // 300 upper-triangular tile pairs
#define EROWS 2
#define THR 4e-3f

// ---- exact f64 slow path: recompute gram from global Xc + f64 MLP --------
// Same values/fma order as the original always-f64 kernel; rare (|m32|<THR).
// Unrolled so global/scalar loads batch up instead of serializing at ~300cy each.
__device__ __attribute__((noinline))
double edge_exact_f64(const double* __restrict__ Xc, const double* __restrict__ wpack,
                      int b, int i, int j, double init) {
    const double* xi0 = Xc + ((size_t)(b * 2 + 0) * NN + i) * 64;
    const double* xj0 = Xc + ((size_t)(b * 2 + 0) * NN + j) * 64;
    const double* xi1 = Xc + ((size_t)(b * 2 + 1) * NN + i) * 64;
    const double* xj1 = Xc + ((size_t)(b * 2 + 1) * NN + j) * 64;
    double p0 = 0.0, p1 = 0.0;
#pragma unroll 4
    for (int d2 = 0; d2 < 32; ++d2) {
        double2 a0 = *(const double2*)&xi0[2 * d2];
        double2 b0 = *(const double2*)&xj0[2 * d2];
        double2 a1 = *(const double2*)&xi1[2 * d2];
        double2 b1 = *(const double2*)&xj1[2 * d2];
        p0 = fma(a0.y, b0.y, fma(a0.x, b0.x, p0));
        p1 = fma(a1.y, b1.y, fma(a1.x, b1.x, p1));
    }
    double m = init;
#pragma unroll 8
    for (int c = 0; c < HH; ++c) {
        double2 wab = *(const double2*)&wpack[4 * c];        // a, b (uniform -> s_load)
        double2 wbw = *(const double2*)&wpack[4 * c + 2];    // beta, wd
        double tt = fma(p1, wab.y, fma(p0, wab.x, wbw.x));
        tt = fmax(tt, 0.0);
        m = fma(tt, wbw.y, m);
    }
    return m;
}

__device__ inline float decide(float m32, const double* __restrict__ Xc,
                               const double* __restrict__ wpack,
                               int b, int i, int j, double init) {
    // |m32 - m64| practical ~4e-4 (f32 gram + f32 MLP); THR = 4e-3 = 10x margin.
    if (__builtin_expect(fabsf(m32) < THR, 0))
        return edge_exact_f64(Xc, wpack, b, i, j, init) > 0.0 ? 1.0f : 0.0f;
    return m32 > 0.0f ? 1.0f : 0.0f;
}

// k1: feats = relu(X@w1+b1)@w2+b2 (f64 accum); Xc (f64) and Xcf (f32) both written.
// block 0 additionally packs the score-MLP weights (f64 + f32).
__global__ __launch_bounds__(128)
void edgefeat_kernel(const float* __restrict__ X,
                     const float* __restrict__ w1, const float* __restrict__ b1,
                     const float* __restrict__ w2, const float* __restrict__ b2,
                     const float* __restrict__ gatep,
                     const float* __restrict__ sm_w1, const float* __restrict__ sm_b1,
                     const float* __restrict__ sm_w2,
                     double* __restrict__ Xc, float* __restrict__ Xcf,
                     double* __restrict__ wpack, float4* __restrict__ wpackf) {
    __shared__ float  Xs[EROWS][FF];
    __shared__ double Hs[EROWS][HH];
    const int h = threadIdx.x;            // 0..127 output column
    const int row0 = blockIdx.x * EROWS;  // global row in [0, B*N)
    for (int r = 0; r < EROWS; ++r) Xs[r][h] = X[(size_t)(row0 + r) * FF + h];
    if (blockIdx.x == 0) {
        // wpack[c] = {w1[0,c], w1[1,c], b1[c], w2[c,1]-w2[c,0]}
        double a  = (double)sm_w1[h];
        double bq = (double)sm_w1[HH + h];
        double be = (double)sm_b1[h];
        double wd = (double)sm_w2[2 * h + 1] - (double)sm_w2[2 * h + 0];
        wpack[4 * h + 0] = a;  wpack[4 * h + 1] = bq;
        wpack[4 * h + 2] = be; wpack[4 * h + 3] = wd;
        wpackf[h] = make_float4((float)a, (float)bq, (float)be, (float)wd);
    }
    __syncthreads();
    double acc[EROWS];
    double bb = (double)b1[h];
    for (int r = 0; r < EROWS; ++r) acc[r] = bb;
    for (int f = 0; f < FF; ++f) {
        double w = (double)w1[f * HH + h];        // coalesced across h
        for (int r = 0; r < EROWS; ++r) acc[r] = fma((double)Xs[r][f], w, acc[r]);
    }
    for (int r = 0; r < EROWS; ++r) Hs[r][h] = acc[r] > 0.0 ? acc[r] : 0.0;
    __syncthreads();
    bb = (double)b2[h];
    for (int r = 0; r < EROWS; ++r) acc[r] = bb;
    for (int c = 0; c < HH; ++c) {
        double w = (double)w2[c * HH + h];
        for (int r = 0; r < EROWS; ++r) acc[r] = fma(Hs[r][c], w, acc[r]);
    }
    const double gate = (double)gatep[0];
    const int k = h & 1, d = h >> 1;
    const int b = row0 / NN;
    const int i0 = row0 % NN;
    for (int r = 0; r < EROWS; ++r) {
        double v = (double)Xs[r][h] + gate * acc[r];
        size_t idx = (((size_t)(b * 2 + k)) * NN + (i0 + r)) * 64 + d;
        Xc[idx]  = v;
        Xcf[idx] = (float)v;
    }
}

// k2: per upper-tri 32x32 tile: f32 gram (LDS, fully unrolled) ->
//     f32 edge MLP (weights via uniform s_load, blocked x8) ->
//     sign decision with rare exact-f64 re-compute -> symmetric write.
__global__ __launch_bounds__(256, 4)
void edge_decide_kernel(const double* __restrict__ Xc,
                        const float* __restrict__ Xcf,
                        const double* __restrict__ wpack,
                        const float4* __restrict__ wpackf,
                        const float* __restrict__ sm_b2,
                        const float* __restrict__ gumbel,
                        float* __restrict__ out) {
    __shared__ float  Ai[2][TS][66];   // stride 66 floats: 2-way bank alias only (free)
    __shared__ float  Aj[2][TS][66];
    __shared__ float  As[TS][TS + 1];
    const int b = blockIdx.y;
    const int t = blockIdx.x;
    // decode upper-triangular pair index: t -> (ti, tj), tj >= ti   (T=24)
    int ti = (int)((49.0 - sqrt(2401.0 - 8.0 * (double)t)) * 0.5);
    int base = ti * (49 - ti) / 2;
    if (t < base) { --ti; base = ti * (49 - ti) / 2; }
    else { int nb = (ti + 1) * (48 - ti) / 2; if (t >= nb) { ++ti; base = nb; } }
    const int tj = t - base + ti;
    const int tid = threadIdx.x;
    const int i0 = ti * TS, j0 = tj * TS;

    // stage f32 Xcf tiles (coalesced float2 global reads)
    for (int q = 0; q < 8; ++q) {
        int flat = tid + 256 * q;        // pair index over (k, r, d2)
        int d2 = flat & 31;
        int r  = (flat >> 5) & 31;
        int k  = flat >> 10;
        size_t rowbase = ((size_t)(b * 2 + k)) * NN;
        float2 vi = *(const float2*)&Xcf[(rowbase + i0 + r) * 64 + 2 * d2];
        *(float2*)&Ai[k][r][2 * d2] = vi;
        float2 vj = *(const float2*)&Xcf[(rowbase + j0 + r) * 64 + 2 * d2];
        *(float2*)&Aj[k][r][2 * d2] = vj;
    }

    const int rh = tid >> 4;         // 0..15
    const int ch = tid & 15;         // 0..15
    const int r0 = rh, r1 = rh + 16;
    const int c0 = 2 * ch, c1 = c0 + 1;

    // issue gumbel loads early (hide ~400cy global latency under the gram loop)
    const double bd = (double)sm_b2[1] - (double)sm_b2[0];
    float4 g0v = *(const float4*)&gumbel[(((size_t)b * NN + i0 + r0) * NN + j0 + c0) * 2];
    float4 g1v = *(const float4*)&gumbel[(((size_t)b * NN + i0 + r1) * NN + j0 + c0) * 2];

    __syncthreads();

    // f32 gram: p[k][re][ce] — fully unrolled, ds_reads batch up
    float p000 = 0.f, p001 = 0.f, p010 = 0.f, p011 = 0.f;
    float p100 = 0.f, p101 = 0.f, p110 = 0.f, p111 = 0.f;
#pragma unroll
    for (int d2 = 0; d2 < 32; ++d2) {
        float2 a00 = *(const float2*)&Ai[0][r0][2 * d2];
        float2 a01 = *(const float2*)&Ai[0][r1][2 * d2];
        float2 a10 = *(const float2*)&Ai[1][r0][2 * d2];
        float2 a11 = *(const float2*)&Ai[1][r1][2 * d2];
        float2 b00 = *(const float2*)&Aj[0][c0][2 * d2];
        float2 b01 = *(const float2*)&Aj[0][c1][2 * d2];
        float2 b10 = *(const float2*)&Aj[1][c0][2 * d2];
        float2 b11 = *(const float2*)&Aj[1][c1][2 * d2];
        p000 = fmaf(a00.y, b00.y, fmaf(a00.x, b00.x, p000));
        p001 = fmaf(a00.y, b01.y, fmaf(a00.x, b01.x, p001));
        p010 = fmaf(a01.y, b00.y, fmaf(a01.x, b00.x, p010));
        p011 = fmaf(a01.y, b01.y, fmaf(a01.x, b01.x, p011));
        p100 = fmaf(a10.y, b10.y, fmaf(a10.x, b10.x, p100));
        p101 = fmaf(a10.y, b11.y, fmaf(a10.x, b11.x, p101));
        p110 = fmaf(a11.y, b10.y, fmaf(a11.x, b10.x, p110));
        p111 = fmaf(a11.y, b11.y, fmaf(a11.x, b11.x, p111));
    }

    // margin init: (b2[1]-b2[0]) + (g1-g0) per edge (f64 kept for exact fallback init)
    double i00 = bd + ((double)g0v.y - (double)g0v.x);
    double i01 = bd + ((double)g0v.w - (double)g0v.z);
    double i10 = bd + ((double)g1v.y - (double)g1v.x);
    double i11 = bd + ((double)g1v.w - (double)g1v.z);

    // f32 edge MLP; weights via uniform global reads (s_load), blocked x8 so the
    // scalar loads issue in batches instead of one ~latency per channel.
    float m00 = (float)i00, m01 = (float)i01, m10 = (float)i10, m11 = (float)i11;
#pragma unroll 1
    for (int c = 0; c < HH; c += 8) {
        float4 w[8];
#pragma unroll
        for (int u = 0; u < 8; ++u) w[u] = wpackf[c + u];
#pragma unroll
        for (int u = 0; u < 8; ++u) {
            float tt;
            tt = fmaf(p100, w[u].y, fmaf(p000, w[u].x, w[u].z)); tt = fmaxf(tt, 0.f); m00 = fmaf(tt, w[u].w, m00);
            tt = fmaf(p101, w[u].y, fmaf(p001, w[u].x, w[u].z)); tt = fmaxf(tt, 0.f); m01 = fmaf(tt, w[u].w, m01);
            tt = fmaf(p110, w[u].y, fmaf(p010, w[u].x, w[u].z)); tt = fmaxf(tt, 0.f); m10 = fmaf(tt, w[u].w, m10);
            tt = fmaf(p111, w[u].y, fmaf(p011, w[u].x, w[u].z)); tt = fmaxf(tt, 0.f); m11 = fmaf(tt, w[u].w, m11);
        }
    }

    const int gi0 = i0 + r0, gi1 = i0 + r1;
    const int gj0 = j0 + c0, gj1 = j0 + c1;
    float A00 = decide(m00, Xc, wpack, b, gi0, gj0, i00);
    float A01 = decide(m01, Xc, wpack, b, gi0, gj1, i01);
    float A10 = decide(m10, Xc, wpack, b, gi1, gj0, i10);
    float A11 = decide(m11, Xc, wpack, b, gi1, gj1, i11);

    As[r0][c0] = A00; As[r0][c1] = A01;
    As[r1][c0] = A10; As[r1][c1] = A11;
    __syncthreads();

    if (ti != tj) {
        // direct tile (i<j guaranteed)
        *(float2*)&out[((size_t)b * NN + gi0) * NN + gj0] = make_float2(A00, A01);
        *(float2*)&out[((size_t)b * NN + gi1) * NN + gj0] = make_float2(A10, A11);
        // transposed tile: out[b, j0+jr, i0+ic] = As[ic][jr]
        float2 t0 = make_float2(As[c0][r0], As[c1][r0]);
        *(float2*)&out[((size_t)b * NN + j0 + r0) * NN + i0 + c0] = t0;
        float2 t1 = make_float2(As[c0][r1], As[c1][r1]);
        *(float2*)&out[((size_t)b * NN + j0 + r1) * NN + i0 + c0] = t1;
    } else {
        // diagonal tile: upper value mirrored, diag = 0
        float v00 = (r0 < c0) ? As[r0][c0] : ((r0 > c0) ? As[c0][r0] : 0.0f);
        float v01 = (r0 < c1) ? As[r0][c1] : ((r0 > c1) ? As[c1][r0] : 0.0f);
        float v10 = (r1 < c0) ? As[r1][c0] : ((r1 > c0) ? As[c0][r1] : 0.0f);
        float v11 = (r1 < c1) ? As[r1][c1] : ((r1 > c1) ? As[c1][r1] : 0.0f);
        *(float2*)&out[((size_t)b * NN + gi0) * NN + gj0] = make_float2(v00, v01);
        *(float2*)&out[((size_t)b * NN + gi1) * NN + gj0] = make_float2(v10, v11);
    }
}

extern "C" void kernel_launch(void* const* d_in, const int* in_sizes, int n_in,
                              void* d_out, int out_size, void* d_ws, size_t ws_size,
                              hipStream_t stream) {
    const float* X      = (const float*)d_in[0];
    const float* ef_w1  = (const float*)d_in[1];
    const float* ef_b1  = (const float*)d_in[2];
    const float* ef_w2  = (const float*)d_in[3];
    const float* ef_b2  = (const float*)d_in[4];
    const float* gate   = (const float*)d_in[5];
    const float* sm_w1  = (const float*)d_in[6];
    const float* sm_b1  = (const float*)d_in[7];
    const float* sm_w2  = (const float*)d_in[8];
    const float* sm_b2  = (const float*)d_in[9];
    const float* gumbel = (const float*)d_in[10];
    float* out = (float*)d_out;

    double* Xc     = (double*)d_ws;                         // 2*2*768*64 doubles = 1.5 MiB
    double* wpack  = Xc + (size_t)BB * 2 * NN * 64;         // 512 doubles
    float4* wpackf = (float4*)(wpack + 4 * HH);             // 128 float4
    float*  Xcf    = (float*)(wpackf + HH);                 // 768 KiB f32 copy

    edgefeat_kernel<<<BB * NN / EROWS, 128, 0, stream>>>(
        X, ef_w1, ef_b1, ef_w2, ef_b2, gate, sm_w1, sm_b1, sm_w2, Xc, Xcf, wpack, wpackf);
    dim3 grid(NPAIR, BB);
    edge_decide_kernel<<<grid, 256, 0, stream>>>(Xc, Xcf, wpack, wpackf, sm_b2, gumbel, out);
}

// Round 4
// 120.466 us; speedup vs baseline: 1.2630x; 1.0945x over previous
//
#include <hip/hip_runtime.h>

#define BB 2
#define NN 768
#define FF 128
#define HH 128
#define TS 32
#define NT (NN / TS)                 // 24 tiles per dim
#define NPAIR (NT * (NT + 1) / 2)    // 300 upper-triangular tile pairs
#define EROWS 2
#define THR 4e-3f

// ---- exact f64 slow path: recompute gram from global Xc + f64 MLP --------
// Same values/fma order as the original always-f64 kernel; executed only in a
// cold branch (|m32| < THR, ~1e-4 of edges). Fully inlined: no call ABI/spills.
__device__ __forceinline__
double edge_exact_f64(const double* __restrict__ Xc, const double* __restrict__ wpack,
                      int b, int i, int j, double init) {
    const double* xi0 = Xc + ((size_t)(b * 2 + 0) * NN + i) * 64;
    const double* xj0 = Xc + ((size_t)(b * 2 + 0) * NN + j) * 64;
    const double* xi1 = Xc + ((size_t)(b * 2 + 1) * NN + i) * 64;
    const double* xj1 = Xc + ((size_t)(b * 2 + 1) * NN + j) * 64;
    double p0 = 0.0, p1 = 0.0;
#pragma unroll 4
    for (int d2 = 0; d2 < 32; ++d2) {
        double2 a0 = *(const double2*)&xi0[2 * d2];
        double2 b0 = *(const double2*)&xj0[2 * d2];
        double2 a1 = *(const double2*)&xi1[2 * d2];
        double2 b1 = *(const double2*)&xj1[2 * d2];
        p0 = fma(a0.y, b0.y, fma(a0.x, b0.x, p0));
        p1 = fma(a1.y, b1.y, fma(a1.x, b1.x, p1));
    }
    double m = init;
#pragma unroll 8
    for (int c = 0; c < HH; ++c) {
        double2 wab = *(const double2*)&wpack[4 * c];        // a, b (uniform -> s_load)
        double2 wbw = *(const double2*)&wpack[4 * c + 2];    // beta, wd
        double tt = fma(p1, wab.y, fma(p0, wab.x, wbw.x));
        tt = fmax(tt, 0.0);
        m = fma(tt, wbw.y, m);
    }
    return m;
}

// k1: feats = relu(X@w1+b1)@w2+b2 (f64 accum); Xc (f64) and Xcf (f32) both written.
// block 0 additionally packs the score-MLP weights (f64 + f32).
__global__ __launch_bounds__(128)
void edgefeat_kernel(const float* __restrict__ X,
                     const float* __restrict__ w1, const float* __restrict__ b1,
                     const float* __restrict__ w2, const float* __restrict__ b2,
                     const float* __restrict__ gatep,
                     const float* __restrict__ sm_w1, const float* __restrict__ sm_b1,
                     const float* __restrict__ sm_w2,
                     double* __restrict__ Xc, float* __restrict__ Xcf,
                     double* __restrict__ wpack, float4* __restrict__ wpackf) {
    __shared__ float  Xs[EROWS][FF];
    __shared__ double Hs[EROWS][HH];
    const int h = threadIdx.x;            // 0..127 output column
    const int row0 = blockIdx.x * EROWS;  // global row in [0, B*N)
    for (int r = 0; r < EROWS; ++r) Xs[r][h] = X[(size_t)(row0 + r) * FF + h];
    if (blockIdx.x == 0) {
        // wpack[c] = {w1[0,c], w1[1,c], b1[c], w2[c,1]-w2[c,0]}
        double a  = (double)sm_w1[h];
        double bq = (double)sm_w1[HH + h];
        double be = (double)sm_b1[h];
        double wd = (double)sm_w2[2 * h + 1] - (double)sm_w2[2 * h + 0];
        wpack[4 * h + 0] = a;  wpack[4 * h + 1] = bq;
        wpack[4 * h + 2] = be; wpack[4 * h + 3] = wd;
        wpackf[h] = make_float4((float)a, (float)bq, (float)be, (float)wd);
    }
    __syncthreads();
    double acc[EROWS];
    double bb = (double)b1[h];
    for (int r = 0; r < EROWS; ++r) acc[r] = bb;
    for (int f = 0; f < FF; ++f) {
        double w = (double)w1[f * HH + h];        // coalesced across h
        for (int r = 0; r < EROWS; ++r) acc[r] = fma((double)Xs[r][f], w, acc[r]);
    }
    for (int r = 0; r < EROWS; ++r) Hs[r][h] = acc[r] > 0.0 ? acc[r] : 0.0;
    __syncthreads();
    bb = (double)b2[h];
    for (int r = 0; r < EROWS; ++r) acc[r] = bb;
    for (int c = 0; c < HH; ++c) {
        double w = (double)w2[c * HH + h];
        for (int r = 0; r < EROWS; ++r) acc[r] = fma(Hs[r][c], w, acc[r]);
    }
    const double gate = (double)gatep[0];
    const int k = h & 1, d = h >> 1;
    const int b = row0 / NN;
    const int i0 = row0 % NN;
    for (int r = 0; r < EROWS; ++r) {
        double v = (double)Xs[r][h] + gate * acc[r];
        size_t idx = (((size_t)(b * 2 + k)) * NN + (i0 + r)) * 64 + d;
        Xc[idx]  = v;
        Xcf[idx] = (float)v;
    }
}

// k2: 512 threads per 32x32 tile. Lane-pair slicing (s = tid&1): each thread does
// half the gram K-dim and half the MLP channels; __shfl_xor(1) butterflies reduce.
// Doubles wave count (4.7/SIMD), halves per-wave critical path. Weights in LDS.
__global__ __launch_bounds__(512, 6)
void edge_decide_kernel(const double* __restrict__ Xc,
                        const float* __restrict__ Xcf,
                        const double* __restrict__ wpack,
                        const float4* __restrict__ wpackf,
                        const float* __restrict__ sm_b2,
                        const float* __restrict__ gumbel,
                        float* __restrict__ out) {
    __shared__ float  Ai[2][TS][66];   // stride 66 floats: 2-way bank alias only (free)
    __shared__ float  Aj[2][TS][66];
    __shared__ float4 Wl[HH];          // packed score-MLP weights {a,b,beta,wd}
    __shared__ float  As[TS][TS + 1];
    const int b = blockIdx.y;
    const int t = blockIdx.x;
    // decode upper-triangular pair index: t -> (ti, tj), tj >= ti   (T=24)
    int ti = (int)((49.0 - sqrt(2401.0 - 8.0 * (double)t)) * 0.5);
    int base = ti * (49 - ti) / 2;
    if (t < base) { --ti; base = ti * (49 - ti) / 2; }
    else { int nb = (ti + 1) * (48 - ti) / 2; if (t >= nb) { ++ti; base = nb; } }
    const int tj = t - base + ti;
    const int tid = threadIdx.x;
    const int i0 = ti * TS, j0 = tj * TS;

    // stage f32 Xcf tiles (coalesced float2 global reads)
    for (int q = 0; q < 4; ++q) {
        int flat = tid + 512 * q;        // pair index over (k, r, d2)
        int dp = flat & 31;
        int r  = (flat >> 5) & 31;
        int k  = flat >> 10;
        size_t rowbase = ((size_t)(b * 2 + k)) * NN;
        *(float2*)&Ai[k][r][2 * dp] = *(const float2*)&Xcf[(rowbase + i0 + r) * 64 + 2 * dp];
        *(float2*)&Aj[k][r][2 * dp] = *(const float2*)&Xcf[(rowbase + j0 + r) * 64 + 2 * dp];
    }
    if (tid < HH) Wl[tid] = wpackf[tid];

    const int s  = tid & 1;          // slice within lane pair
    const int e  = tid >> 1;         // edge-quad id 0..255
    const int rh = e >> 4;           // 0..15
    const int ch = e & 15;           // 0..15
    const int r0 = rh, r1 = rh + 16;
    const int c0 = 2 * ch, c1 = c0 + 1;
    const int gi0 = i0 + r0, gi1 = i0 + r1;
    const int gj0 = j0 + c0, gj1 = j0 + c1;

    // issue gumbel loads early (s==0 lanes only; hide global latency under gram)
    float4 g0v = make_float4(0.f, 0.f, 0.f, 0.f);
    float4 g1v = make_float4(0.f, 0.f, 0.f, 0.f);
    if (s == 0) {
        g0v = *(const float4*)&gumbel[(((size_t)b * NN + gi0) * NN + gj0) * 2];
        g1v = *(const float4*)&gumbel[(((size_t)b * NN + gi1) * NN + gj0) * 2];
    }
    __syncthreads();

    // f32 gram, K-sliced: slice s covers d2 = s + 2*it (interleaved keeps banks 2-way)
    float p000 = 0.f, p001 = 0.f, p010 = 0.f, p011 = 0.f;
    float p100 = 0.f, p101 = 0.f, p110 = 0.f, p111 = 0.f;
#pragma unroll
    for (int it = 0; it < 16; ++it) {
        const int d2 = s + 2 * it;
        float2 a00 = *(const float2*)&Ai[0][r0][2 * d2];
        float2 a01 = *(const float2*)&Ai[0][r1][2 * d2];
        float2 a10 = *(const float2*)&Ai[1][r0][2 * d2];
        float2 a11 = *(const float2*)&Ai[1][r1][2 * d2];
        float2 b00 = *(const float2*)&Aj[0][c0][2 * d2];
        float2 b01 = *(const float2*)&Aj[0][c1][2 * d2];
        float2 b10 = *(const float2*)&Aj[1][c0][2 * d2];
        float2 b11 = *(const float2*)&Aj[1][c1][2 * d2];
        p000 = fmaf(a00.y, b00.y, fmaf(a00.x, b00.x, p000));
        p001 = fmaf(a00.y, b01.y, fmaf(a00.x, b01.x, p001));
        p010 = fmaf(a01.y, b00.y, fmaf(a01.x, b00.x, p010));
        p011 = fmaf(a01.y, b01.y, fmaf(a01.x, b01.x, p011));
        p100 = fmaf(a10.y, b10.y, fmaf(a10.x, b10.x, p100));
        p101 = fmaf(a10.y, b11.y, fmaf(a10.x, b11.x, p101));
        p110 = fmaf(a11.y, b10.y, fmaf(a11.x, b10.x, p110));
        p111 = fmaf(a11.y, b11.y, fmaf(a11.x, b11.x, p111));
    }
    // butterfly-reduce p over the lane pair; both lanes get the full dot
    p000 += __shfl_xor(p000, 1); p001 += __shfl_xor(p001, 1);
    p010 += __shfl_xor(p010, 1); p011 += __shfl_xor(p011, 1);
    p100 += __shfl_xor(p100, 1); p101 += __shfl_xor(p101, 1);
    p110 += __shfl_xor(p110, 1); p111 += __shfl_xor(p111, 1);

    // f32 edge MLP, channel-sliced: slice s covers c = s + 2*it; weights via LDS
    // broadcast (2 uniform b128 addresses/wave, disjoint banks).
    float m00 = 0.f, m01 = 0.f, m10 = 0.f, m11 = 0.f;
#pragma unroll 8
    for (int it = 0; it < 64; ++it) {
        float4 w = Wl[s + 2 * it];     // {a, b, beta, wd}
        float tt;
        tt = fmaf(p100, w.y, fmaf(p000, w.x, w.z)); tt = fmaxf(tt, 0.f); m00 = fmaf(tt, w.w, m00);
        tt = fmaf(p101, w.y, fmaf(p001, w.x, w.z)); tt = fmaxf(tt, 0.f); m01 = fmaf(tt, w.w, m01);
        tt = fmaf(p110, w.y, fmaf(p010, w.x, w.z)); tt = fmaxf(tt, 0.f); m10 = fmaf(tt, w.w, m10);
        tt = fmaf(p111, w.y, fmaf(p011, w.x, w.z)); tt = fmaxf(tt, 0.f); m11 = fmaf(tt, w.w, m11);
    }
    m00 += __shfl_xor(m00, 1); m01 += __shfl_xor(m01, 1);
    m10 += __shfl_xor(m10, 1); m11 += __shfl_xor(m11, 1);

    if (s == 0) {
        const double bd = (double)sm_b2[1] - (double)sm_b2[0];
        double i00 = bd + ((double)g0v.y - (double)g0v.x);
        double i01 = bd + ((double)g0v.w - (double)g0v.z);
        double i10 = bd + ((double)g1v.y - (double)g1v.x);
        double i11 = bd + ((double)g1v.w - (double)g1v.z);
        float f00 = m00 + (float)i00;
        float f01 = m01 + (float)i01;
        float f10 = m10 + (float)i10;
        float f11 = m11 + (float)i11;
        float A00 = f00 > 0.f ? 1.f : 0.f;
        float A01 = f01 > 0.f ? 1.f : 0.f;
        float A10 = f10 > 0.f ? 1.f : 0.f;
        float A11 = f11 > 0.f ? 1.f : 0.f;
        float fm = fminf(fminf(fabsf(f00), fabsf(f01)), fminf(fabsf(f10), fabsf(f11)));
        if (__builtin_expect(fm < THR, 0)) {
            // rare: exact f64 re-decide (bit-identical to the original f64 kernel)
            if (fabsf(f00) < THR) A00 = edge_exact_f64(Xc, wpack, b, gi0, gj0, i00) > 0.0 ? 1.f : 0.f;
            if (fabsf(f01) < THR) A01 = edge_exact_f64(Xc, wpack, b, gi0, gj1, i01) > 0.0 ? 1.f : 0.f;
            if (fabsf(f10) < THR) A10 = edge_exact_f64(Xc, wpack, b, gi1, gj0, i10) > 0.0 ? 1.f : 0.f;
            if (fabsf(f11) < THR) A11 = edge_exact_f64(Xc, wpack, b, gi1, gj1, i11) > 0.0 ? 1.f : 0.f;
        }
        As[r0][c0] = A00; As[r0][c1] = A01;
        As[r1][c0] = A10; As[r1][c1] = A11;
    }
    __syncthreads();

    if (s == 0) {
        float A00 = As[r0][c0], A01 = As[r0][c1];
        float A10 = As[r1][c0], A11 = As[r1][c1];
        if (ti != tj) {
            // direct tile (i<j guaranteed)
            *(float2*)&out[((size_t)b * NN + gi0) * NN + gj0] = make_float2(A00, A01);
            *(float2*)&out[((size_t)b * NN + gi1) * NN + gj0] = make_float2(A10, A11);
            // transposed tile: out[b, j0+jr, i0+ic] = As[ic][jr]
            float2 t0 = make_float2(As[c0][r0], As[c1][r0]);
            *(float2*)&out[((size_t)b * NN + j0 + r0) * NN + i0 + c0] = t0;
            float2 t1 = make_float2(As[c0][r1], As[c1][r1]);
            *(float2*)&out[((size_t)b * NN + j0 + r1) * NN + i0 + c0] = t1;
        } else {
            // diagonal tile: upper value mirrored, diag = 0
            float v00 = (r0 < c0) ? A00 : ((r0 > c0) ? As[c0][r0] : 0.0f);
            float v01 = (r0 < c1) ? A01 : ((r0 > c1) ? As[c1][r0] : 0.0f);
            float v10 = (r1 < c0) ? A10 : ((r1 > c0) ? As[c0][r1] : 0.0f);
            float v11 = (r1 < c1) ? A11 : ((r1 > c1) ? As[c1][r1] : 0.0f);
            *(float2*)&out[((size_t)b * NN + gi0) * NN + gj0] = make_float2(v00, v01);
            *(float2*)&out[((size_t)b * NN + gi1) * NN + gj0] = make_float2(v10, v11);
        }
    }
}

extern "C" void kernel_launch(void* const* d_in, const int* in_sizes, int n_in,
                              void* d_out, int out_size, void* d_ws, size_t ws_size,
                              hipStream_t stream) {
    const float* X      = (const float*)d_in[0];
    const float* ef_w1  = (const float*)d_in[1];
    const float* ef_b1  = (const float*)d_in[2];
    const float* ef_w2  = (const float*)d_in[3];
    const float* ef_b2  = (const float*)d_in[4];
    const float* gate   = (const float*)d_in[5];
    const float* sm_w1  = (const float*)d_in[6];
    const float* sm_b1  = (const float*)d_in[7];
    const float* sm_w2  = (const float*)d_in[8];
    const float* sm_b2  = (const float*)d_in[9];
    const float* gumbel = (const float*)d_in[10];
    float* out = (float*)d_out;

    double* Xc     = (double*)d_ws;                         // 2*2*768*64 doubles = 1.5 MiB
    double* wpack  = Xc + (size_t)BB * 2 * NN * 64;         // 512 doubles
    float4* wpackf = (float4*)(wpack + 4 * HH);             // 128 float4
    float*  Xcf    = (float*)(wpackf + HH);                 // 768 KiB f32 copy

    edgefeat_kernel<<<BB * NN / EROWS, 128, 0, stream>>>(
        X, ef_w1, ef_b1, ef_w2, ef_b2, gate, sm_w1, sm_b1, sm_w2, Xc, Xcf, wpack, wpackf);
    dim3 grid(NPAIR, BB);
    edge_decide_kernel<<<grid, 512, 0, stream>>>(Xc, Xcf, wpack, wpackf, sm_b2, gumbel, out);
}